// Round 1
// baseline (1310.892 us; speedup 1.0000x reference)
//
#include <hip/hip_runtime.h>

// MeshConv: g = [x0, x1+x3, x2+x4, |x1-x3|, |x2-x4|] stacked as H=5,
// then NCHW conv with OIHW W of shape (16,16,1,5), VALID -> out (4,16,5,F-4), + bias.
//
// Layout facts:
//   x[n,i,f,k]  = x[((n*16+i)*F + f)*5 + k]        (K=5 innermost, contiguous)
//   W[o,i,0,kw] = W[(o*16+i)*5 + kw]
//   y[n,o,h,w]  = y[((n*16+o)*5 + h)*(F-4) + w]
//   y[n,o,h,w]  = b[o] + sum_i sum_kw W[o,i,kw] * g[n,i,h,w+kw]
//
// v2 strategy (o-blocking to fix LDS-instruction-pipe bound):
//   - 64-thread (1-wave) blocks, TF=64 positions, LDS tile 21.76 KB -> 7 blocks/CU,
//     independent waves (no cross-wave barrier coupling).
//   - Each thread computes ONE w position but ALL 16 o and all 5 h:
//     the 25 ds_read_b32 per i now feed 400 FMAs (16 FMA/read vs 4 before),
//     moving the bottleneck from the CU-shared LDS pipe to the FMA pipe.
//   - W accesses are wave-uniform -> s_load; o split in two 8-wide halves to
//     keep live SGPRs ~40. FMAs written as f32x2 to invite v_pk_fma_f32.

using f32x2 = __attribute__((ext_vector_type(2))) float;

constexpr int NN   = 4;
constexpr int CIN  = 16;
constexpr int COUT = 16;
constexpr int FF   = 500000;
constexpr int KK   = 5;
constexpr int FO   = FF - 4;     // 499996
constexpr int TF   = 64;         // output positions per block
constexpr int TFH  = TF + 4;     // staged positions (halo)

__global__ __launch_bounds__(64)
void meshconv_kernel(const float* __restrict__ x,
                     const float* __restrict__ W,
                     const float* __restrict__ b,
                     float* __restrict__ out)
{
    __shared__ float g_lds[CIN * TFH * 5];   // [i][fl][h], 21760 B

    const int n  = blockIdx.y;
    const int w0 = blockIdx.x * TF;
    const int t  = threadIdx.x;              // 0..63, wl == t

    // ---- Stage: load x, build g rows, write LDS ----
    // 16*68 = 1088 (i, fl) pairs; 17 per thread; each pair = 5 contiguous x floats.
    for (int p = t; p < CIN * TFH; p += 64) {
        const int i  = p / TFH;
        const int fl = p - i * TFH;
        const int f  = w0 + fl;
        float x0 = 0.f, x1 = 0.f, x2 = 0.f, x3 = 0.f, x4 = 0.f;
        if (f < FF) {
            const float* xp = x + ((n * CIN + i) * (size_t)FF + f) * KK;
            x0 = xp[0]; x1 = xp[1]; x2 = xp[2]; x3 = xp[3]; x4 = xp[4];
        }
        float* gp = g_lds + p * 5;
        gp[0] = x0;
        gp[1] = x1 + x3;
        gp[2] = x2 + x4;
        gp[3] = fabsf(x1 - x3);
        gp[4] = fabsf(x2 - x4);
    }
    __syncthreads();

    // ---- Compute: acc[h][o-pair], all 16 o per thread ----
    f32x2 acc[5][8];
    #pragma unroll
    for (int h = 0; h < 5; ++h)
        #pragma unroll
        for (int j = 0; j < 8; ++j)
            acc[h][j] = f32x2{b[2 * j], b[2 * j + 1]};

    const int wl = t;

    #pragma unroll 2
    for (int i = 0; i < CIN; ++i) {
        // 25-float g window for this (i, wl): fl in [wl, wl+4], h in [0,5)
        const float* gi = g_lds + (i * TFH + wl) * 5;
        float g25[25];
        #pragma unroll
        for (int q = 0; q < 25; ++q) g25[q] = gi[q];

        // Two o-halves of 8 to bound live W values (~40 scalars each)
        #pragma unroll
        for (int half = 0; half < 2; ++half) {
            f32x2 ws[4][5];   // 4 o-pairs x 5 kw, wave-uniform indices
            #pragma unroll
            for (int j = 0; j < 4; ++j)
                #pragma unroll
                for (int kw = 0; kw < KK; ++kw) {
                    const int o0 = half * 8 + 2 * j;
                    ws[j][kw] = f32x2{W[((o0    ) * CIN + i) * KK + kw],
                                      W[((o0 + 1) * CIN + i) * KK + kw]};
                }

            #pragma unroll
            for (int kw = 0; kw < KK; ++kw)
                #pragma unroll
                for (int h = 0; h < 5; ++h) {
                    const float gv = g25[kw * 5 + h];
                    const f32x2 gg = {gv, gv};
                    #pragma unroll
                    for (int j = 0; j < 4; ++j)
                        acc[h][half * 4 + j] =
                            __builtin_elementwise_fma(ws[j][kw], gg,
                                                      acc[h][half * 4 + j]);
                }
        }
    }

    // ---- Epilogue: store (bias already folded into acc init) ----
    const int w = w0 + wl;
    if (w < FO) {
        #pragma unroll
        for (int j = 0; j < 8; ++j) {
            const int o = 2 * j;
            #pragma unroll
            for (int h = 0; h < 5; ++h) {
                out[((n * COUT + o    ) * 5 + h) * (size_t)FO + w] = acc[h][j].x;
                out[((n * COUT + o + 1) * 5 + h) * (size_t)FO + w] = acc[h][j].y;
            }
        }
    }
}

extern "C" void kernel_launch(void* const* d_in, const int* in_sizes, int n_in,
                              void* d_out, int out_size, void* d_ws, size_t ws_size,
                              hipStream_t stream)
{
    const float* x = (const float*)d_in[0];
    const float* W = (const float*)d_in[1];
    const float* b = (const float*)d_in[2];
    float* out = (float*)d_out;

    const int ntiles = (FO + TF - 1) / TF;   // 7813
    dim3 grid(ntiles, NN);
    dim3 block(64);
    meshconv_kernel<<<grid, block, 0, stream>>>(x, W, b, out);
}